// Round 28
// baseline (73.950 us; speedup 1.0000x reference)
//
#include <hip/hip_runtime.h>
#include <math.h>

// CasperNet R28: B=131072, D=256, H=64, O=10.
// R27 (two-kernel split, 59.6us) disproved the co-located-latency theory;
// fused R20 (46.8us) remains best. Last untested lever: per-block FIXED
// cost amortization. Every fused variant pays {sW staging (5120 scattered
// global loads) + sUB build + dispatch slot} once per 128 rows, and grid
// 1024 at 2 blocks/CU runs TWO sequential dispatch rounds.
// R28: TM=256 -- each wave processes tile A then tile B SEQUENTIALLY
// (same registers, unlike R18's concurrent 2-tile that serialized via
// pressure); grid 512 = exactly 2 blocks/CU x 256 CUs -> ONE round,
// staging amortized 2x. Dedicated sT patches (R21-verified barrier-free)
// keep sW live for tile B. All math byte-identical to R19/R20.
// Layout (verified R5): MFMA C: col=lane&15, row=(lane>>4)*4+reg;
// A-frag: lane(lm,lg) = A[row=lm][k=lg*8+j].

#define DIMD 256
#define DIMH 64
#define DIMO 10
#define DT   320
#define NT   5        // 5 n-tiles of 16 = 80 cols (74 used)
#define TM   256      // rows per block: 8 waves x 2 sequential 16-row tiles
#define BLOCK 512

typedef __attribute__((ext_vector_type(4))) float f32x4;
typedef __attribute__((ext_vector_type(8))) short bf16x8;

__device__ inline unsigned short f2bf(float f) {   // RNE, deterministic
    union { float f; unsigned u; } v; v.f = f;
    unsigned r = v.u + 0x7FFFu + ((v.u >> 16) & 1u);
    return (unsigned short)(r >> 16);
}
__device__ inline float sigm(float s) {
    return __builtin_amdgcn_rcpf(1.0f + __expf(-s));   // v_rcp_f32
}

__global__ __launch_bounds__(BLOCK, 2) void caspernet_kernel(
    const float* __restrict__ x,    // [B, 256]
    const float* __restrict__ Wh,   // [64, 320]
    const float* __restrict__ bh,   // [64]
    const float* __restrict__ Wo,   // [10, 320]
    const float* __restrict__ bo,   // [10]
    float* __restrict__ out,        // [B, 10]
    int B)
{
    __shared__ short sW[80 * DIMD];     // bf16 [n][k], swizzled;     40960B
    __shared__ short sUB[640 * 8];      // 10 slots x 64 lanes x 8;   10240B
    __shared__ float sT[8 * 320];       // per-wave 16x20 patches;    10240B
    __shared__ float sBias[80];         //                              320B
                                        // total ~60.3KB -> 2 blocks/CU

    const int tid = threadIdx.x;

    // ---- stage W1 = [Wh_x; Wo_x] as bf16, swizzled (short4 writes) ----
    for (int idx = tid; idx < 80 * 64; idx += BLOCK) {   // 80 rows x 64 float4
        const int n = idx >> 6, k0 = (idx & 63) * 4;
        float4 v = make_float4(0.f, 0.f, 0.f, 0.f);
        if (n < DIMH)      v = *reinterpret_cast<const float4*>(Wh + n * DT + k0);
        else if (n < 74)   v = *reinterpret_cast<const float4*>(Wo + (n - 64) * DT + k0);
        const int kz = k0 ^ ((n & 7) << 3);
        short4 sv;
        sv.x = (short)f2bf(v.x); sv.y = (short)f2bf(v.y);
        sv.z = (short)f2bf(v.z); sv.w = (short)f2bf(v.w);
        *reinterpret_cast<short4*>(sW + n * DIMD + kz) = sv;   // 8B aligned
    }
    // ---- build B-frag blob in-block ----
    for (int e = tid; e < 640; e += BLOCK) {
        const int p = e >> 6, l2 = e & 63;
        int g, t;
        if      (p < 4) { g = 0; t = p + 1; }
        else if (p < 7) { g = 1; t = p - 2; }      // p=4,5,6 -> t=2,3,4
        else if (p < 9) { g = 2; t = p - 4; }      // p=7,8   -> t=3,4
        else            { g = 3; t = 4;     }
        const int lm2 = l2 & 15, lg2 = l2 >> 4;
        const int col = t * 16 + lm2;
        short4 lo = {0, 0, 0, 0}, hi = {0, 0, 0, 0};
        if (lg2 < 2 && col < 74) {
            const float* src = (col < DIMH)
                ? (Wh + col * DT + DIMD + g * 16 + lg2 * 8)
                : (Wo + (col - DIMH) * DT + DIMD + g * 16 + lg2 * 8);
            const float4 a = *reinterpret_cast<const float4*>(src);
            const float4 b = *reinterpret_cast<const float4*>(src + 4);
            lo.x = (short)f2bf(a.x); lo.y = (short)f2bf(a.y);
            lo.z = (short)f2bf(a.z); lo.w = (short)f2bf(a.w);
            hi.x = (short)f2bf(b.x); hi.y = (short)f2bf(b.y);
            hi.z = (short)f2bf(b.z); hi.w = (short)f2bf(b.w);
        }
        *reinterpret_cast<short4*>(sUB + e * 8)     = lo;
        *reinterpret_cast<short4*>(sUB + e * 8 + 4) = hi;
    }
    if (tid < 80) sBias[tid] = (tid < 64) ? bh[tid] : ((tid < 74) ? bo[tid - 64] : 0.f);
    __syncthreads();                    // the only block-wide barrier

    const int l  = tid & 63;
    const int w  = tid >> 6;            // wave 0..7
    const int lm = l & 15, lg = l >> 4;
    float* tb = sT + w * 320;           // 16x20 f32 patch, wave-private

    // ---- two sequential 16-row tiles per wave (amortized staging) ----
    #pragma unroll 1
    for (int u = 0; u < 2; ++u) {
        const size_t rowA = (size_t)blockIdx.x * TM + u * 128 + w * 16 + lm;
        const float* xr = x + rowA * DIMD + lg * 8;

        f32x4 acc[NT];
        #pragma unroll
        for (int t = 0; t < NT; ++t) acc[t] = (f32x4){0.f, 0.f, 0.f, 0.f};

        // ---- phase 1 ----
        #pragma unroll
        for (int ks = 0; ks < 8; ++ks) {
            const float4 xa = *reinterpret_cast<const float4*>(xr + ks * 32);
            const float4 xb = *reinterpret_cast<const float4*>(xr + ks * 32 + 4);
            bf16x8 af;
            af[0] = (short)f2bf(xa.x); af[1] = (short)f2bf(xa.y);
            af[2] = (short)f2bf(xa.z); af[3] = (short)f2bf(xa.w);
            af[4] = (short)f2bf(xb.x); af[5] = (short)f2bf(xb.y);
            af[6] = (short)f2bf(xb.z); af[7] = (short)f2bf(xb.w);
            #pragma unroll
            for (int t = 0; t < NT; ++t) {
                const int n = t * 16 + lm;
                const int kz = (lg * 8 + ks * 32) ^ ((n & 7) << 3);
                const bf16x8 bf = *reinterpret_cast<const bf16x8*>(sW + n * DIMD + kz);
                acc[t] = __builtin_amdgcn_mfma_f32_16x16x32_bf16(af, bf, acc[t], 0, 0, 0);
            }
        }
        #pragma unroll
        for (int t = 0; t < NT; ++t) {
            const float bt = sBias[t * 16 + lm];
            acc[t][0] += bt; acc[t][1] += bt; acc[t][2] += bt; acc[t][3] += bt;
        }

        // ---- phase 2: blocked cascade on wave-private patch ----
        #pragma unroll
        for (int g = 0; g < 4; ++g) {
            #pragma unroll
            for (int r = 0; r < 4; ++r)
                tb[(lg * 4 + r) * 20 + lm] = acc[g][r];
            float s[16];
            #pragma unroll
            for (int q = 0; q < 4; ++q) {
                const f32x4 v = *reinterpret_cast<const f32x4*>(tb + lm * 20 + q * 4);
                s[q * 4 + 0] = v[0]; s[q * 4 + 1] = v[1];
                s[q * 4 + 2] = v[2]; s[q * 4 + 3] = v[3];
            }
            const float* cg = Wh + (g * 16) * DT + DIMD + g * 16;  // s_loads
            float h[16];
            h[0] = sigm(s[0]);
            #pragma unroll
            for (int k = 1; k < 16; ++k) {
                float a_ = s[k];
                #pragma unroll
                for (int m = 0; m < k; ++m)
                    a_ = fmaf(cg[k * DT + m], h[m], a_);
                h[k] = sigm(a_);
            }
            bf16x8 haf;
            #pragma unroll
            for (int j = 0; j < 8; ++j) {
                const float hv = (lg == 0) ? h[j] : ((lg == 1) ? h[8 + j] : 0.f);
                haf[j] = (short)f2bf(hv);
            }
            const int pbase = (g == 0) ? 0 : (g == 1) ? 4 : (g == 2) ? 7 : 9;
            #pragma unroll
            for (int t = g + 1; t < NT; ++t) {
                const bf16x8 bf = *reinterpret_cast<const bf16x8*>(
                    sUB + (pbase + t - g - 1) * 512 + l * 8);
                acc[t] = __builtin_amdgcn_mfma_f32_16x16x32_bf16(haf, bf, acc[t], 0, 0, 0);
            }
        }

        // ---- store head tile (cols 64..73 = C-tile 4) ----
        if (lm < DIMO) {
            const size_t orow0 = (size_t)blockIdx.x * TM + u * 128 + w * 16 + lg * 4;
            #pragma unroll
            for (int r = 0; r < 4; ++r)
                out[(orow0 + r) * DIMO + lm] = acc[4][r];
        }
    }
}

extern "C" void kernel_launch(void* const* d_in, const int* in_sizes, int n_in,
                              void* d_out, int out_size, void* d_ws, size_t ws_size,
                              hipStream_t stream) {
    const float* x  = (const float*)d_in[0];
    const float* Wh = (const float*)d_in[1];
    const float* bh = (const float*)d_in[2];
    const float* Wo = (const float*)d_in[3];
    const float* bo = (const float*)d_in[4];
    float* out = (float*)d_out;

    const int B = in_sizes[0] / DIMD;      // 131072
    const int grid = B / TM;               // 512 = 2 blocks/CU x 256 CUs

    hipLaunchKernelGGL(caspernet_kernel, dim3(grid), dim3(BLOCK), 0, stream,
                       x, Wh, bh, Wo, bo, out, B);
}